// Round 17
// baseline (401.720 us; speedup 1.0000x reference)
//
#include <hip/hip_runtime.h>
#include <math.h>

#define NT 4096
#define DM 1024
#define DF 2048
#define NEXP 16

typedef __attribute__((ext_vector_type(8))) short bf16x8;
typedef __attribute__((ext_vector_type(4))) float f32x4;

__device__ __forceinline__ unsigned short f2bf(float f) {
  unsigned int u = __builtin_bit_cast(unsigned int, f);
  u += 0x7fffu + ((u >> 16) & 1u);
  return (unsigned short)(u >> 16);
}
__device__ __forceinline__ float bf2f(unsigned short s) {
  unsigned int u = ((unsigned int)s) << 16;
  return __builtin_bit_cast(float, u);
}

__device__ __forceinline__ void gload_lds16(const void* g, void* l) {
  __builtin_amdgcn_global_load_lds(
      (__attribute__((address_space(1))) void*)g,
      (__attribute__((address_space(3))) void*)l, 16, 0, 0);
}

// fast gelu (tanh form), max abs err ~3e-4 vs exact erf gelu
__device__ __forceinline__ float gelu_f(float v) {
  float u = v * (0.7978845608f + 0.0356774081f * v * v);
  float t = 1.0f - 2.0f / (__expf(2.0f * u) + 1.0f);
  return 0.5f * v * (1.0f + t);
}

__device__ __forceinline__ void softmax4(float* v) {
  float m = fmaxf(fmaxf(v[0], v[1]), fmaxf(v[2], v[3]));
  float s = 0.f;
#pragma unroll
  for (int j = 0; j < 4; ++j) { v[j] = expf(v[j] - m); s += v[j]; }
  float inv = 1.f / s;
#pragma unroll
  for (int j = 0; j < 4; ++j) v[j] *= inv;
}

// ---------------- router phase A: per-token mask+weights, NO atomics ----------------
__global__ __launch_bounds__(256) void router2_kernel(
    const float* __restrict__ x, const float* __restrict__ Wg,
    const float* __restrict__ We, unsigned int* __restrict__ emask,
    float* __restrict__ eweight, unsigned short* __restrict__ xb) {
  int n = blockIdx.x;
  int tid = threadIdx.x;
  int c0 = tid * 4;
  float4 xv = *(const float4*)(x + (size_t)n * DM + c0);
  if (xb) {
    ushort4 o = make_ushort4(f2bf(xv.x), f2bf(xv.y), f2bf(xv.z), f2bf(xv.w));
    *(ushort4*)(xb + (size_t)n * DM + c0) = o;
  }
  float xa[4] = {xv.x, xv.y, xv.z, xv.w};
  float acc[20];
#pragma unroll
  for (int j = 0; j < 20; ++j) acc[j] = 0.f;
#pragma unroll
  for (int j = 0; j < 4; ++j) {
    int c = c0 + j;
    float4 wg = *(const float4*)(Wg + c * 4);
    acc[0] += xa[j] * wg.x; acc[1] += xa[j] * wg.y;
    acc[2] += xa[j] * wg.z; acc[3] += xa[j] * wg.w;
#pragma unroll
    for (int q = 0; q < 4; ++q) {
      float4 we = *(const float4*)(We + c * 16 + q * 4);
      acc[4 + q * 4 + 0] += xa[j] * we.x;
      acc[4 + q * 4 + 1] += xa[j] * we.y;
      acc[4 + q * 4 + 2] += xa[j] * we.z;
      acc[4 + q * 4 + 3] += xa[j] * we.w;
    }
  }
#pragma unroll
  for (int j = 0; j < 20; ++j) {
    float v = acc[j];
#pragma unroll
    for (int s = 32; s; s >>= 1) v += __shfl_xor(v, s, 64);
    acc[j] = v;
  }
  __shared__ float red[4][20];
  int lane = tid & 63, wv = tid >> 6;
  if (lane == 0) {
#pragma unroll
    for (int j = 0; j < 20; ++j) red[wv][j] = acc[j];
  }
  __syncthreads();
  if (tid == 0) {
    float t[20];
#pragma unroll
    for (int j = 0; j < 20; ++j)
      t[j] = red[0][j] + red[1][j] + red[2][j] + red[3][j];
    float gp[4] = {t[0], t[1], t[2], t[3]};
    softmax4(gp);
    float ep[16];
#pragma unroll
    for (int g = 0; g < 4; ++g) {
      float tt[4] = {t[4 + g * 4], t[5 + g * 4], t[6 + g * 4], t[7 + g * 4]};
      softmax4(tt);
#pragma unroll
      for (int i = 0; i < 4; ++i) ep[g * 4 + i] = tt[i];
    }
    float fp[16];
    bool valid[16];
    int nsel = 0;
#pragma unroll
    for (int g = 0; g < 4; ++g) {
      bool gm = gp[g] >= 0.25f;
#pragma unroll
      for (int i = 0; i < 4; ++i) {
        int e = g * 4 + i;
        bool em = ep[e] >= 0.25f;
        valid[e] = gm && em;
        fp[e] = gp[g] * ep[e];
        nsel += valid[e] ? 1 : 0;
      }
    }
    int m1 = 0; float v1 = -1.f;
#pragma unroll
    for (int e = 0; e < 16; ++e) if (fp[e] > v1) { v1 = fp[e]; m1 = e; }
    int m2 = -1; float v2 = -2.f;
#pragma unroll
    for (int e = 0; e < 16; ++e) if (e != m1 && fp[e] > v2) { v2 = fp[e]; m2 = e; }
    bool use_topk = nsel < 2;
    float sel[16]; float s = 0.f;
#pragma unroll
    for (int e = 0; e < 16; ++e) {
      bool msk = use_topk ? (e == m1 || e == m2) : valid[e];
      sel[e] = msk ? fp[e] : 0.f;
      s += sel[e];
      valid[e] = msk;
    }
    float inv = 1.f / fmaxf(s, 1e-9f);
    unsigned int mbits = 0;
    float wv16[16];
#pragma unroll
    for (int e = 0; e < 16; ++e) {
      mbits |= (valid[e] ? 1u : 0u) << e;
      wv16[e] = valid[e] ? sel[e] * inv : 0.f;
    }
    emask[n] = mbits;
#pragma unroll
    for (int i = 0; i < 4; ++i)
      *(float4*)(eweight + (size_t)n * 16 + i * 4) =
          make_float4(wv16[i * 4], wv16[i * 4 + 1], wv16[i * 4 + 2], wv16[i * 4 + 3]);
  }
}

// ---------------- router phase B: deterministic ballot compaction ----------------
__global__ __launch_bounds__(256) void compact_kernel(
    const unsigned int* __restrict__ emask, const float* __restrict__ eweight,
    int* __restrict__ counts, int* __restrict__ lists, float* __restrict__ wl,
    int* __restrict__ slotpos) {
  int e = blockIdx.x;
  int tid = threadIdx.x, lane = tid & 63, wv = tid >> 6;
  __shared__ int wcnt[4];
  int running = 0;
  for (int base = 0; base < NT; base += 256) {
    int n = base + tid;
    bool p = (emask[n] >> e) & 1u;
    unsigned long long bal = __ballot(p);
    int cnt = __popcll(bal);
    if (lane == 0) wcnt[wv] = cnt;
    __syncthreads();
    int off = running;
#pragma unroll
    for (int w = 0; w < 4; ++w)
      if (w < wv) off += wcnt[w];
    int tot = wcnt[0] + wcnt[1] + wcnt[2] + wcnt[3];
    if (p) {
      int pos = off + (int)__popcll(bal & ((1ull << lane) - 1ull));
      lists[e * NT + pos] = n;
      wl[e * NT + pos] = eweight[(size_t)n * 16 + e];
      slotpos[e * NT + n] = pos;
    }
    running += tot;
    __syncthreads();
  }
  if (tid == 0) counts[e] = running;
}

// prefix: 256-padded h row bases (+ worklist for fallback path)
__global__ void prefix_kernel(const int* __restrict__ counts, int* __restrict__ base,
                              int* __restrict__ ent, int* __restrict__ nent) {
  if (threadIdx.x == 0 && blockIdx.x == 0) {
    int acc = 0, n = 0;
    for (int e = 0; e < NEXP; ++e) {
      base[e] = acc;
      acc += (counts[e] + 255) & ~255;
      int mt = (counts[e] + 127) >> 7;
      for (int m = 0; m < mt; ++m) ent[n++] = (e << 16) | m;
    }
    *nent = n;
  }
}

// in fp32 [E][K][N] -> out bf16 [E][N][K], 64x64 LDS tiles
__global__ __launch_bounds__(256) void wtrans_kernel(
    const float* __restrict__ in, unsigned short* __restrict__ outp, int K, int N) {
  int e = blockIdx.z;
  int n0 = blockIdx.x * 64;
  int k0 = blockIdx.y * 64;
  const float* src = in + (size_t)e * K * N;
  unsigned short* dst = outp + (size_t)e * K * N;
  __shared__ unsigned short t[64][65];
  int tid = threadIdx.x;
#pragma unroll
  for (int it = 0; it < 4; ++it) {
    int idx = it * 256 + tid;
    int r = idx >> 4, c4 = (idx & 15) << 2;
    float4 v = *(const float4*)(src + (size_t)(k0 + r) * N + n0 + c4);
    t[r][c4 + 0] = f2bf(v.x);
    t[r][c4 + 1] = f2bf(v.y);
    t[r][c4 + 2] = f2bf(v.z);
    t[r][c4 + 3] = f2bf(v.w);
  }
  __syncthreads();
#pragma unroll
  for (int it = 0; it < 4; ++it) {
    int idx = it * 256 + tid;
    int r = idx >> 4, c4 = (idx & 15) << 2;
    ushort4 o;
    o.x = t[c4 + 0][r]; o.y = t[c4 + 1][r];
    o.z = t[c4 + 2][r]; o.w = t[c4 + 3][r];
    *(ushort4*)(dst + (size_t)(n0 + r) * K + k0 + c4) = o;
  }
}

// ======== 128x128 XCD-static persistent GEMMs (4 waves, 32KB LDS, 5 blk/CU) ========
// grid 1280; xcd = b&7 hosts experts xcd, xcd+8; slot = b>>3 (160 slots/XCD);
// m-fastest tile order so concurrent same-XCD slots share the B (weight) n-panel.

// GEMM1: h[hbase+slot, :] = gelu(xb[tok] @ w1t[e]^T + b1[e]); w1t layout [E][DF][DM]
__global__ __launch_bounds__(256, 5) void ffn1s_kernel(
    const unsigned short* __restrict__ xb, const unsigned short* __restrict__ wt,
    const float* __restrict__ b1, const int* __restrict__ counts,
    const int* __restrict__ lists, const int* __restrict__ base,
    unsigned short* __restrict__ h, int cap) {
  const int NN = DF / 128;   // 16 n-tiles
  const int NSLOT = 160;
  int b = blockIdx.x;
  int xcd = b & 7, slot = b >> 3;
  int e0 = xcd, e1 = xcd + 8;
  int c0 = counts[e0], c1 = counts[e1];
  int mt0 = (c0 + 127) >> 7, mt1 = (c1 + 127) >> 7;
  int T0 = mt0 * NN, T = T0 + mt1 * NN;

  __shared__ unsigned short lA[128 * 64];
  __shared__ unsigned short lB[128 * 64];

  int tid = threadIdx.x, lane = tid & 63, wid = tid >> 6;
  int wm = wid >> 1, wn = wid & 1;
  int lrow = lane & 15, lk = lane >> 4;
  int chunk = lane & 7, row_l = lane >> 3;

  for (int k = slot; k < T; k += NSLOT) {
    int e, mti, nt, count;
    if (k < T0) { e = e0; nt = k / mt0; mti = k % mt0; count = c0; }
    else        { int kk = k - T0; e = e1; nt = kk / mt1; mti = kk % mt1; count = c1; }
    int m0 = mti * 128, n0 = nt * 128;
    int hbase = base[e];
    if (hbase + m0 + 128 > cap) continue;
    const unsigned short* we = wt + (size_t)e * DM * DF;  // [DF][DM]
    const int* lst = lists + e * NT + m0;

    const char* asrc[4];
    const char* bsrc[4];
#pragma unroll
    for (int c = 0; c < 4; ++c) {
      int r = wid * 32 + c * 8 + row_l;
      int sc = chunk ^ (r & 7);
      int rr = (m0 + r < count) ? r : 0;
      int tok = lst[rr];
      asrc[c] = (const char*)xb + (size_t)tok * DM * 2 + sc * 16;
      bsrc[c] = (const char*)we + (size_t)(n0 + r) * DM * 2 + sc * 16;
    }

    f32x4 acc[4][4];
#pragma unroll
    for (int m = 0; m < 4; ++m)
#pragma unroll
      for (int n = 0; n < 4; ++n) acc[m][n] = (f32x4)0.0f;

    for (int kt = 0; kt < DM / 64; ++kt) {
      __syncthreads();
#pragma unroll
      for (int c = 0; c < 4; ++c) {
        gload_lds16(asrc[c] + kt * 128, (void*)(lA + (wid * 32 + c * 8) * 64));
        gload_lds16(bsrc[c] + kt * 128, (void*)(lB + (wid * 32 + c * 8) * 64));
      }
      __syncthreads();
#pragma unroll
      for (int ks = 0; ks < 2; ++ks) {
        bf16x8 af[4], bfr[4];
#pragma unroll
        for (int m = 0; m < 4; ++m) {
          int row = wm * 64 + m * 16 + lrow;
          int off = row * 128 + (((ks * 64) + lk * 16) ^ ((row & 7) << 4));
          af[m] = *(const bf16x8*)((const char*)lA + off);
        }
#pragma unroll
        for (int n = 0; n < 4; ++n) {
          int row = wn * 64 + n * 16 + lrow;
          int off = row * 128 + (((ks * 64) + lk * 16) ^ ((row & 7) << 4));
          bfr[n] = *(const bf16x8*)((const char*)lB + off);
        }
#pragma unroll
        for (int m = 0; m < 4; ++m)
#pragma unroll
          for (int n = 0; n < 4; ++n)
            acc[m][n] = __builtin_amdgcn_mfma_f32_16x16x32_bf16(af[m], bfr[n], acc[m][n], 0, 0, 0);
      }
    }
#pragma unroll
    for (int m = 0; m < 4; ++m) {
      int rbase = hbase + m0 + wm * 64 + m * 16 + lk * 4;
#pragma unroll
      for (int n = 0; n < 4; ++n) {
        int col = n0 + wn * 64 + n * 16 + lrow;
        float bias = b1[e * DF + col];
#pragma unroll
        for (int j = 0; j < 4; ++j) {
          float v = acc[m][n][j] + bias;
          h[(size_t)(rbase + j) * DF + col] = f2bf(gelu_f(v));
        }
      }
    }
  }
}

// GEMM2 (y-path): y[hbase+slot, :] = h @ w2t[e]^T  (bf16, no bias, no atomics)
__global__ __launch_bounds__(256, 5) void ffn2y_kernel(
    const unsigned short* __restrict__ h, const unsigned short* __restrict__ wt,
    const int* __restrict__ counts, const int* __restrict__ base,
    unsigned short* __restrict__ y, int cap) {
  const int NN = DM / 128;  // 8 n-tiles
  const int NSLOT = 160;
  int b = blockIdx.x;
  int xcd = b & 7, slot = b >> 3;
  int e0 = xcd, e1 = xcd + 8;
  int c0 = counts[e0], c1 = counts[e1];
  int mt0 = (c0 + 127) >> 7, mt1 = (c1 + 127) >> 7;
  int T0 = mt0 * NN, T = T0 + mt1 * NN;

  __shared__ unsigned short lA[128 * 64];
  __shared__ unsigned short lB[128 * 64];

  int tid = threadIdx.x, lane = tid & 63, wid = tid >> 6;
  int wm = wid >> 1, wn = wid & 1;
  int lrow = lane & 15, lk = lane >> 4;
  int chunk = lane & 7, row_l = lane >> 3;

  for (int k = slot; k < T; k += NSLOT) {
    int e, mti, nt, count;
    if (k < T0) { e = e0; nt = k / mt0; mti = k % mt0; count = c0; }
    else        { int kk = k - T0; e = e1; nt = kk / mt1; mti = kk % mt1; count = c1; }
    int m0 = mti * 128, n0 = nt * 128;
    int hbase = base[e];
    if (hbase + m0 + 128 > cap) continue;
    const unsigned short* we = wt + (size_t)e * DM * DF;  // [DM][DF]

    const char* asrc[4];
    const char* bsrc[4];
#pragma unroll
    for (int c = 0; c < 4; ++c) {
      int r = wid * 32 + c * 8 + row_l;
      int sc = chunk ^ (r & 7);
      asrc[c] = (const char*)h + (size_t)(hbase + m0 + r) * DF * 2 + sc * 16;
      bsrc[c] = (const char*)we + (size_t)(n0 + r) * DF * 2 + sc * 16;
    }

    f32x4 acc[4][4];
#pragma unroll
    for (int m = 0; m < 4; ++m)
#pragma unroll
      for (int n = 0; n < 4; ++n) acc[m][n] = (f32x4)0.0f;

    for (int kt = 0; kt < DF / 64; ++kt) {
      __syncthreads();
#pragma unroll
      for (int c = 0; c < 4; ++c) {
        gload_lds16(asrc[c] + kt * 128, (void*)(lA + (wid * 32 + c * 8) * 64));
        gload_lds16(bsrc[c] + kt * 128, (void*)(lB + (wid * 32 + c * 8) * 64));
      }
      __syncthreads();
#pragma unroll
      for (int ks = 0; ks < 2; ++ks) {
        bf16x8 af[4], bfr[4];
#pragma unroll
        for (int m = 0; m < 4; ++m) {
          int row = wm * 64 + m * 16 + lrow;
          int off = row * 128 + (((ks * 64) + lk * 16) ^ ((row & 7) << 4));
          af[m] = *(const bf16x8*)((const char*)lA + off);
        }
#pragma unroll
        for (int n = 0; n < 4; ++n) {
          int row = wn * 64 + n * 16 + lrow;
          int off = row * 128 + (((ks * 64) + lk * 16) ^ ((row & 7) << 4));
          bfr[n] = *(const bf16x8*)((const char*)lB + off);
        }
#pragma unroll
        for (int m = 0; m < 4; ++m)
#pragma unroll
          for (int n = 0; n < 4; ++n)
            acc[m][n] = __builtin_amdgcn_mfma_f32_16x16x32_bf16(af[m], bfr[n], acc[m][n], 0, 0, 0);
      }
    }
#pragma unroll
    for (int m = 0; m < 4; ++m) {
      int rbase = hbase + m0 + wm * 64 + m * 16 + lk * 4;
      int lcl = m0 + wm * 64 + m * 16 + lk * 4;
#pragma unroll
      for (int n = 0; n < 4; ++n) {
        int col = n0 + wn * 64 + n * 16 + lrow;
#pragma unroll
        for (int j = 0; j < 4; ++j) {
          if (lcl + j < count)
            y[(size_t)(rbase + j) * DM + col] = f2bf(acc[m][n][j]);
        }
      }
    }
  }
}

// final: out[n] = sum_e w * (y[row_e] + b2[e])
__global__ __launch_bounds__(256) void reduce_kernel(
    const unsigned int* __restrict__ emask, const float* __restrict__ eweight,
    const int* __restrict__ slotpos, const int* __restrict__ base,
    const unsigned short* __restrict__ y, const float* __restrict__ b2,
    float* __restrict__ out) {
  int n = blockIdx.x;
  int tid = threadIdx.x;
  int c = tid * 4;
  unsigned int mask = emask[n];
  float4 accv = make_float4(0.f, 0.f, 0.f, 0.f);
  while (mask) {
    int e = __ffs(mask) - 1;
    mask &= mask - 1;
    float w = eweight[(size_t)n * 16 + e];
    int row = base[e] + slotpos[e * NT + n];
    ushort4 yv = *(const ushort4*)(y + (size_t)row * DM + c);
    float4 bv = *(const float4*)(b2 + e * DM + c);
    accv.x += w * (bf2f(yv.x) + bv.x);
    accv.y += w * (bf2f(yv.y) + bv.y);
    accv.z += w * (bf2f(yv.z) + bv.z);
    accv.w += w * (bf2f(yv.w) + bv.w);
  }
  *(float4*)(out + (size_t)n * DM + c) = accv;
}

// GEMM2 (atomic fallback, static mapping): out[tok] += w * (h @ w2t[e]^T + b2[e])
__global__ __launch_bounds__(256, 5) void ffn2s_kernel(
    const unsigned short* __restrict__ h, const unsigned short* __restrict__ wt,
    const float* __restrict__ b2, const int* __restrict__ counts,
    const int* __restrict__ lists, const int* __restrict__ base,
    const float* __restrict__ wl, float* __restrict__ out, int cap) {
  const int NN = DM / 128;
  const int NSLOT = 160;
  int b = blockIdx.x;
  int xcd = b & 7, slot = b >> 3;
  int e0 = xcd, e1 = xcd + 8;
  int c0 = counts[e0], c1 = counts[e1];
  int mt0 = (c0 + 127) >> 7, mt1 = (c1 + 127) >> 7;
  int T0 = mt0 * NN, T = T0 + mt1 * NN;

  __shared__ unsigned short lA[128 * 64];
  __shared__ unsigned short lB[128 * 64];

  int tid = threadIdx.x, lane = tid & 63, wid = tid >> 6;
  int wm = wid >> 1, wn = wid & 1;
  int lrow = lane & 15, lk = lane >> 4;
  int chunk = lane & 7, row_l = lane >> 3;

  for (int k = slot; k < T; k += NSLOT) {
    int e, mti, nt, count;
    if (k < T0) { e = e0; nt = k / mt0; mti = k % mt0; count = c0; }
    else        { int kk = k - T0; e = e1; nt = kk / mt1; mti = kk % mt1; count = c1; }
    int m0 = mti * 128, n0 = nt * 128;
    int hbase = base[e];
    if (hbase + m0 + 128 > cap) continue;
    const unsigned short* we = wt + (size_t)e * DM * DF;

    const char* asrc[4];
    const char* bsrc[4];
#pragma unroll
    for (int c = 0; c < 4; ++c) {
      int r = wid * 32 + c * 8 + row_l;
      int sc = chunk ^ (r & 7);
      asrc[c] = (const char*)h + (size_t)(hbase + m0 + r) * DF * 2 + sc * 16;
      bsrc[c] = (const char*)we + (size_t)(n0 + r) * DF * 2 + sc * 16;
    }

    f32x4 acc[4][4];
#pragma unroll
    for (int m = 0; m < 4; ++m)
#pragma unroll
      for (int n = 0; n < 4; ++n) acc[m][n] = (f32x4)0.0f;

    for (int kt = 0; kt < DF / 64; ++kt) {
      __syncthreads();
#pragma unroll
      for (int c = 0; c < 4; ++c) {
        gload_lds16(asrc[c] + kt * 128, (void*)(lA + (wid * 32 + c * 8) * 64));
        gload_lds16(bsrc[c] + kt * 128, (void*)(lB + (wid * 32 + c * 8) * 64));
      }
      __syncthreads();
#pragma unroll
      for (int ks = 0; ks < 2; ++ks) {
        bf16x8 af[4], bfr[4];
#pragma unroll
        for (int m = 0; m < 4; ++m) {
          int row = wm * 64 + m * 16 + lrow;
          int off = row * 128 + (((ks * 64) + lk * 16) ^ ((row & 7) << 4));
          af[m] = *(const bf16x8*)((const char*)lA + off);
        }
#pragma unroll
        for (int n = 0; n < 4; ++n) {
          int row = wn * 64 + n * 16 + lrow;
          int off = row * 128 + (((ks * 64) + lk * 16) ^ ((row & 7) << 4));
          bfr[n] = *(const bf16x8*)((const char*)lB + off);
        }
#pragma unroll
        for (int m = 0; m < 4; ++m)
#pragma unroll
          for (int n = 0; n < 4; ++n)
            acc[m][n] = __builtin_amdgcn_mfma_f32_16x16x32_bf16(af[m], bfr[n], acc[m][n], 0, 0, 0);
      }
    }
#pragma unroll
    for (int m = 0; m < 4; ++m) {
      int rbase = m0 + wm * 64 + m * 16 + lk * 4;
#pragma unroll
      for (int n = 0; n < 4; ++n) {
        int col = n0 + wn * 64 + n * 16 + lrow;
        float bias = b2[e * DM + col];
#pragma unroll
        for (int j = 0; j < 4; ++j) {
          int sl = rbase + j;
          if (sl < count) {
            int tok = lists[e * NT + sl];
            float w = wl[e * NT + sl];
            atomicAdd(out + (size_t)tok * DM + col, w * (acc[m][n][j] + bias));
          }
        }
      }
    }
  }
}

// ---------------- fallback GEMMs (fp32 reg-staged, 128^2, small-ws) ----------------
__global__ __launch_bounds__(256) void ffn1_kernel(
    const float* __restrict__ x, const float* __restrict__ w1,
    const float* __restrict__ b1, const int* __restrict__ counts,
    const int* __restrict__ lists, const int* __restrict__ base,
    unsigned short* __restrict__ h, int cap, int e_arg) {
  int e = (e_arg >= 0) ? e_arg : (int)blockIdx.z;
  int count = counts[e];
  int m0 = blockIdx.y * 128;
  if (m0 >= count) return;
  int hbase = base[e];
  if (hbase + m0 + 128 > cap) return;
  int n0 = blockIdx.x * 128;
  const float* w1e = w1 + (size_t)e * DM * DF;
  const int* lst = lists + e * NT + m0;
  __shared__ unsigned short lA[128 * 64];
  __shared__ unsigned short lB[128 * 64];
  int tid = threadIdx.x;
  int lane = tid & 63, wid = tid >> 6;
  int wm = wid >> 1, wn = wid & 1;
  int lrow = lane & 15, lk = lane >> 4;
  f32x4 acc[4][4];
#pragma unroll
  for (int m = 0; m < 4; ++m)
#pragma unroll
    for (int n = 0; n < 4; ++n) acc[m][n] = (f32x4)0.0f;
  for (int kt = 0; kt < DM / 64; ++kt) {
    int k0 = kt * 64;
    __syncthreads();
#pragma unroll
    for (int p = 0; p < 8; ++p) {
      int idx = p * 256 + tid;
      int r = idx >> 4, c4 = idx & 15;
      int tok = (m0 + r < count) ? lst[r] : lst[0];
      float4 v = *(const float4*)(x + (size_t)tok * DM + k0 + c4 * 4);
      ushort4 bv = make_ushort4(f2bf(v.x), f2bf(v.y), f2bf(v.z), f2bf(v.w));
      int off = r * 128 + ((c4 * 8) ^ ((r & 7) << 4));
      *(ushort4*)((char*)lA + off) = bv;
    }
#pragma unroll
    for (int p = 0; p < 16; ++p) {
      int idx = p * 256 + tid;
      int n = idx & 127, k2 = idx >> 7;
      const float* bp = w1e + (size_t)(k0 + 2 * k2) * DF + n0 + n;
      ushort2 bv = make_ushort2(f2bf(bp[0]), f2bf(bp[DF]));
      int off = n * 128 + ((k2 * 4) ^ ((n & 7) << 4));
      *(ushort2*)((char*)lB + off) = bv;
    }
    __syncthreads();
#pragma unroll
    for (int ks = 0; ks < 2; ++ks) {
      bf16x8 af[4], bfr[4];
#pragma unroll
      for (int m = 0; m < 4; ++m) {
        int row = wm * 64 + m * 16 + lrow;
        int off = row * 128 + (((ks * 64) + lk * 16) ^ ((row & 7) << 4));
        af[m] = *(const bf16x8*)((const char*)lA + off);
      }
#pragma unroll
      for (int n = 0; n < 4; ++n) {
        int row = wn * 64 + n * 16 + lrow;
        int off = row * 128 + (((ks * 64) + lk * 16) ^ ((row & 7) << 4));
        bfr[n] = *(const bf16x8*)((const char*)lB + off);
      }
#pragma unroll
      for (int m = 0; m < 4; ++m)
#pragma unroll
        for (int n = 0; n < 4; ++n)
          acc[m][n] = __builtin_amdgcn_mfma_f32_16x16x32_bf16(af[m], bfr[n], acc[m][n], 0, 0, 0);
    }
  }
#pragma unroll
  for (int m = 0; m < 4; ++m) {
    int rbase = hbase + m0 + wm * 64 + m * 16 + lk * 4;
#pragma unroll
    for (int n = 0; n < 4; ++n) {
      int col = n0 + wn * 64 + n * 16 + lrow;
      float bias = b1[e * DF + col];
#pragma unroll
      for (int j = 0; j < 4; ++j) {
        float v = acc[m][n][j] + bias;
        h[(size_t)(rbase + j) * DF + col] = f2bf(gelu_f(v));
      }
    }
  }
}

__global__ __launch_bounds__(256) void ffn2_kernel(
    const unsigned short* __restrict__ h, const float* __restrict__ w2,
    const float* __restrict__ b2, const int* __restrict__ counts,
    const int* __restrict__ lists, const int* __restrict__ base,
    const float* __restrict__ wl, float* __restrict__ out, int cap, int e_arg) {
  int e = (e_arg >= 0) ? e_arg : (int)blockIdx.z;
  int count = counts[e];
  int m0 = blockIdx.y * 128;
  if (m0 >= count) return;
  int hbase = base[e];
  if (hbase + m0 + 128 > cap) return;
  int n0 = blockIdx.x * 128;
  const float* w2e = w2 + (size_t)e * DF * DM;
  __shared__ unsigned short lA[128 * 64];
  __shared__ unsigned short lB[128 * 64];
  int tid = threadIdx.x;
  int lane = tid & 63, wid = tid >> 6;
  int wm = wid >> 1, wn = wid & 1;
  int lrow = lane & 15, lk = lane >> 4;
  f32x4 acc[4][4];
#pragma unroll
  for (int m = 0; m < 4; ++m)
#pragma unroll
    for (int n = 0; n < 4; ++n) acc[m][n] = (f32x4)0.0f;
  for (int kt = 0; kt < DF / 64; ++kt) {
    int k0 = kt * 64;
    __syncthreads();
#pragma unroll
    for (int p = 0; p < 8; ++p) {
      int idx = p * 256 + tid;
      int r = idx >> 4, c4 = idx & 15;
      ushort4 v = *(const ushort4*)(h + (size_t)(hbase + m0 + r) * DF + k0 + c4 * 4);
      int off = r * 128 + ((c4 * 8) ^ ((r & 7) << 4));
      *(ushort4*)((char*)lA + off) = v;
    }
#pragma unroll
    for (int p = 0; p < 16; ++p) {
      int idx = p * 256 + tid;
      int n = idx & 127, k2 = idx >> 7;
      const float* bp = w2e + (size_t)(k0 + 2 * k2) * DM + n0 + n;
      ushort2 bv = make_ushort2(f2bf(bp[0]), f2bf(bp[DM]));
      int off = n * 128 + ((k2 * 4) ^ ((n & 7) << 4));
      *(ushort2*)((char*)lB + off) = bv;
    }
    __syncthreads();
#pragma unroll
    for (int ks = 0; ks < 2; ++ks) {
      bf16x8 af[4], bfr[4];
#pragma unroll
      for (int m = 0; m < 4; ++m) {
        int row = wm * 64 + m * 16 + lrow;
        int off = row * 128 + (((ks * 64) + lk * 16) ^ ((row & 7) << 4));
        af[m] = *(const bf16x8*)((const char*)lA + off);
      }
#pragma unroll
      for (int n = 0; n < 4; ++n) {
        int row = wn * 64 + n * 16 + lrow;
        int off = row * 128 + (((ks * 64) + lk * 16) ^ ((row & 7) << 4));
        bfr[n] = *(const bf16x8*)((const char*)lB + off);
      }
#pragma unroll
      for (int m = 0; m < 4; ++m)
#pragma unroll
        for (int n = 0; n < 4; ++n)
          acc[m][n] = __builtin_amdgcn_mfma_f32_16x16x32_bf16(af[m], bfr[n], acc[m][n], 0, 0, 0);
    }
  }
#pragma unroll
  for (int m = 0; m < 4; ++m) {
    int rbase = m0 + wm * 64 + m * 16 + lk * 4;
#pragma unroll
    for (int n = 0; n < 4; ++n) {
      int col = n0 + wn * 64 + n * 16 + lrow;
      float bias = b2[e * DM + col];
#pragma unroll
      for (int j = 0; j < 4; ++j) {
        int slot = rbase + j;
        if (slot < count) {
          int tok = lists[e * NT + slot];
          float w = wl[e * NT + slot];
          atomicAdd(out + (size_t)tok * DM + col, w * (acc[m][n][j] + bias));
        }
      }
    }
  }
}

extern "C" void kernel_launch(void* const* d_in, const int* in_sizes, int n_in,
                              void* d_out, int out_size, void* d_ws, size_t ws_size,
                              hipStream_t stream) {
  const float* x  = (const float*)d_in[0];
  const float* Wg = (const float*)d_in[1];
  const float* We = (const float*)d_in[2];
  const float* w1 = (const float*)d_in[3];
  const float* b1 = (const float*)d_in[4];
  const float* w2 = (const float*)d_in[5];
  const float* b2 = (const float*)d_in[6];
  float* out = (float*)d_out;

  char* ws = (char*)d_ws;
  int* counts = (int*)ws;                        // 64 B
  int* base   = (int*)(ws + 256);                // 64 B
  int* nent   = (int*)(ws + 576);                // 1 int
  int* ent    = (int*)(ws + 1024);               // 2 KB worklist (fallback)
  unsigned int* emask = (unsigned int*)(ws + 4096);            // 16 KB
  int* lists  = (int*)(ws + 32768);                            // 256 KB
  float* wl   = (float*)(ws + 32768 + NEXP * NT * 4);          // 256 KB
  float* eweight = (float*)(ws + 32768 + 2 * NEXP * NT * 4);   // 256 KB
  int* slotpos   = (int*)(ws + 32768 + 3 * NEXP * NT * 4);     // 256 KB

  const size_t OFF_XB = 2u << 20;                               // 2 MB
  const size_t OFF_WT = OFF_XB + ((size_t)NT * DM * 2);         // +8 MB
  const size_t OFF_H  = OFF_WT + ((size_t)NEXP * DM * DF * 2);  // +64 MB
  long cap6 = ((long)ws_size - (long)OFF_H) / (DF * 2 + DM * 2);
  long cap4 = ((long)ws_size - (long)OFF_H) / (DF * 2);
  bool fast = (cap4 >= 20000);

  unsigned short* xb_router = fast ? (unsigned short*)(ws + OFF_XB) : (unsigned short*)0;

  hipMemsetAsync(out, 0, (size_t)NT * DM * sizeof(float), stream);
  hipMemsetAsync(ws, 0, 1024, stream);
  router2_kernel<<<NT, 256, 0, stream>>>(x, Wg, We, emask, eweight, xb_router);
  compact_kernel<<<NEXP, 256, 0, stream>>>(emask, eweight, counts, lists, wl, slotpos);

  if (fast) {
    unsigned short* xb = (unsigned short*)(ws + OFF_XB);
    unsigned short* wt = (unsigned short*)(ws + OFF_WT);
    unsigned short* h  = (unsigned short*)(ws + OFF_H);
    prefix_kernel<<<1, 64, 0, stream>>>(counts, base, ent, nent);
    wtrans_kernel<<<dim3(DF / 64, DM / 64, NEXP), 256, 0, stream>>>(w1, wt, DM, DF);
    if (cap6 >= 20000) {
      // atomic-free path: y + reduce
      int cap = (int)(cap6 > 65536 ? 65536 : cap6);
      unsigned short* y = (unsigned short*)(ws + OFF_H + (size_t)cap * DF * 2);
      ffn1s_kernel<<<1280, 256, 0, stream>>>(xb, wt, b1, counts, lists, base, h, cap);
      wtrans_kernel<<<dim3(DM / 64, DF / 64, NEXP), 256, 0, stream>>>(w2, wt, DF, DM);
      ffn2y_kernel<<<1280, 256, 0, stream>>>(h, wt, counts, base, y, cap);
      reduce_kernel<<<NT, 256, 0, stream>>>(emask, eweight, slotpos, base, y, b2, out);
    } else {
      // static mapping + atomic scatter
      int cap = (int)(cap4 > 65536 ? 65536 : cap4);
      ffn1s_kernel<<<1280, 256, 0, stream>>>(xb, wt, b1, counts, lists, base, h, cap);
      wtrans_kernel<<<dim3(DM / 64, DF / 64, NEXP), 256, 0, stream>>>(w2, wt, DF, DM);
      ffn2s_kernel<<<1280, 256, 0, stream>>>(h, wt, b2, counts, lists, base, wl, out, cap);
    }
  } else {
    unsigned short* h = (unsigned short*)(ws + OFF_XB);
    long cap_rows = ((long)ws_size - (long)OFF_XB) / (DF * 2);
    if (cap_rows >= 24576) {
      int cap = (int)(cap_rows > 65536 ? 65536 : cap_rows);
      prefix_kernel<<<1, 64, 0, stream>>>(counts, base, ent, nent);
      ffn1_kernel<<<dim3(DF / 128, NT / 128, NEXP), 256, 0, stream>>>(
          x, w1, b1, counts, lists, base, h, cap, -1);
      ffn2_kernel<<<dim3(DM / 128, NT / 128, NEXP), 256, 0, stream>>>(
          h, w2, b2, counts, lists, base, wl, out, cap, -1);
    } else {
      hipMemsetAsync(base, 0, 64, stream);
      prefix_kernel<<<1, 64, 0, stream>>>(counts, base, ent, nent);
      for (int e = 0; e < NEXP; ++e) {
        ffn1_kernel<<<dim3(DF / 128, NT / 128, 1), 256, 0, stream>>>(
            x, w1, b1, counts, lists, base, h, NT, e);
        ffn2_kernel<<<dim3(DM / 128, NT / 128, 1), 256, 0, stream>>>(
            h, w2, b2, counts, lists, base, wl, out, NT, e);
      }
    }
  }
}

// Round 18
// 300.851 us; speedup vs baseline: 1.3353x; 1.3353x over previous
//
#include <hip/hip_runtime.h>
#include <math.h>

#define NT 4096
#define DM 1024
#define DF 2048
#define NEXP 16

typedef __attribute__((ext_vector_type(8))) short bf16x8;
typedef __attribute__((ext_vector_type(4))) float f32x4;

__device__ __forceinline__ unsigned short f2bf(float f) {
  unsigned int u = __builtin_bit_cast(unsigned int, f);
  u += 0x7fffu + ((u >> 16) & 1u);
  return (unsigned short)(u >> 16);
}
__device__ __forceinline__ float bf2f(unsigned short s) {
  unsigned int u = ((unsigned int)s) << 16;
  return __builtin_bit_cast(float, u);
}

__device__ __forceinline__ void gload_lds16(const void* g, void* l) {
  __builtin_amdgcn_global_load_lds(
      (__attribute__((address_space(1))) void*)g,
      (__attribute__((address_space(3))) void*)l, 16, 0, 0);
}

// fast gelu (tanh form), max abs err ~3e-4 vs exact erf gelu
__device__ __forceinline__ float gelu_f(float v) {
  float u = v * (0.7978845608f + 0.0356774081f * v * v);
  float t = 1.0f - 2.0f / (__expf(2.0f * u) + 1.0f);
  return 0.5f * v * (1.0f + t);
}

__device__ __forceinline__ void softmax4(float* v) {
  float m = fmaxf(fmaxf(v[0], v[1]), fmaxf(v[2], v[3]));
  float s = 0.f;
#pragma unroll
  for (int j = 0; j < 4; ++j) { v[j] = expf(v[j] - m); s += v[j]; }
  float inv = 1.f / s;
#pragma unroll
  for (int j = 0; j < 4; ++j) v[j] *= inv;
}

// ---------------- router phase A: per-token mask+weights, NO atomics ----------------
__global__ __launch_bounds__(256) void router2_kernel(
    const float* __restrict__ x, const float* __restrict__ Wg,
    const float* __restrict__ We, unsigned int* __restrict__ emask,
    float* __restrict__ eweight, unsigned short* __restrict__ xb) {
  int n = blockIdx.x;
  int tid = threadIdx.x;
  int c0 = tid * 4;
  float4 xv = *(const float4*)(x + (size_t)n * DM + c0);
  if (xb) {
    ushort4 o = make_ushort4(f2bf(xv.x), f2bf(xv.y), f2bf(xv.z), f2bf(xv.w));
    *(ushort4*)(xb + (size_t)n * DM + c0) = o;
  }
  float xa[4] = {xv.x, xv.y, xv.z, xv.w};
  float acc[20];
#pragma unroll
  for (int j = 0; j < 20; ++j) acc[j] = 0.f;
#pragma unroll
  for (int j = 0; j < 4; ++j) {
    int c = c0 + j;
    float4 wg = *(const float4*)(Wg + c * 4);
    acc[0] += xa[j] * wg.x; acc[1] += xa[j] * wg.y;
    acc[2] += xa[j] * wg.z; acc[3] += xa[j] * wg.w;
#pragma unroll
    for (int q = 0; q < 4; ++q) {
      float4 we = *(const float4*)(We + c * 16 + q * 4);
      acc[4 + q * 4 + 0] += xa[j] * we.x;
      acc[4 + q * 4 + 1] += xa[j] * we.y;
      acc[4 + q * 4 + 2] += xa[j] * we.z;
      acc[4 + q * 4 + 3] += xa[j] * we.w;
    }
  }
#pragma unroll
  for (int j = 0; j < 20; ++j) {
    float v = acc[j];
#pragma unroll
    for (int s = 32; s; s >>= 1) v += __shfl_xor(v, s, 64);
    acc[j] = v;
  }
  __shared__ float red[4][20];
  int lane = tid & 63, wv = tid >> 6;
  if (lane == 0) {
#pragma unroll
    for (int j = 0; j < 20; ++j) red[wv][j] = acc[j];
  }
  __syncthreads();
  if (tid == 0) {
    float t[20];
#pragma unroll
    for (int j = 0; j < 20; ++j)
      t[j] = red[0][j] + red[1][j] + red[2][j] + red[3][j];
    float gp[4] = {t[0], t[1], t[2], t[3]};
    softmax4(gp);
    float ep[16];
#pragma unroll
    for (int g = 0; g < 4; ++g) {
      float tt[4] = {t[4 + g * 4], t[5 + g * 4], t[6 + g * 4], t[7 + g * 4]};
      softmax4(tt);
#pragma unroll
      for (int i = 0; i < 4; ++i) ep[g * 4 + i] = tt[i];
    }
    float fp[16];
    bool valid[16];
    int nsel = 0;
#pragma unroll
    for (int g = 0; g < 4; ++g) {
      bool gm = gp[g] >= 0.25f;
#pragma unroll
      for (int i = 0; i < 4; ++i) {
        int e = g * 4 + i;
        bool em = ep[e] >= 0.25f;
        valid[e] = gm && em;
        fp[e] = gp[g] * ep[e];
        nsel += valid[e] ? 1 : 0;
      }
    }
    int m1 = 0; float v1 = -1.f;
#pragma unroll
    for (int e = 0; e < 16; ++e) if (fp[e] > v1) { v1 = fp[e]; m1 = e; }
    int m2 = -1; float v2 = -2.f;
#pragma unroll
    for (int e = 0; e < 16; ++e) if (e != m1 && fp[e] > v2) { v2 = fp[e]; m2 = e; }
    bool use_topk = nsel < 2;
    float sel[16]; float s = 0.f;
#pragma unroll
    for (int e = 0; e < 16; ++e) {
      bool msk = use_topk ? (e == m1 || e == m2) : valid[e];
      sel[e] = msk ? fp[e] : 0.f;
      s += sel[e];
      valid[e] = msk;
    }
    float inv = 1.f / fmaxf(s, 1e-9f);
    unsigned int mbits = 0;
    float wv16[16];
#pragma unroll
    for (int e = 0; e < 16; ++e) {
      mbits |= (valid[e] ? 1u : 0u) << e;
      wv16[e] = valid[e] ? sel[e] * inv : 0.f;
    }
    emask[n] = mbits;
#pragma unroll
    for (int i = 0; i < 4; ++i)
      *(float4*)(eweight + (size_t)n * 16 + i * 4) =
          make_float4(wv16[i * 4], wv16[i * 4 + 1], wv16[i * 4 + 2], wv16[i * 4 + 3]);
  }
}

// ---------------- router phase B: deterministic ballot compaction ----------------
__global__ __launch_bounds__(256) void compact_kernel(
    const unsigned int* __restrict__ emask, const float* __restrict__ eweight,
    int* __restrict__ counts, int* __restrict__ lists, float* __restrict__ wl,
    int* __restrict__ slotpos) {
  int e = blockIdx.x;
  int tid = threadIdx.x, lane = tid & 63, wv = tid >> 6;
  __shared__ int wcnt[4];
  int running = 0;
  for (int base = 0; base < NT; base += 256) {
    int n = base + tid;
    bool p = (emask[n] >> e) & 1u;
    unsigned long long bal = __ballot(p);
    int cnt = __popcll(bal);
    if (lane == 0) wcnt[wv] = cnt;
    __syncthreads();
    int off = running;
#pragma unroll
    for (int w = 0; w < 4; ++w)
      if (w < wv) off += wcnt[w];
    int tot = wcnt[0] + wcnt[1] + wcnt[2] + wcnt[3];
    if (p) {
      int pos = off + (int)__popcll(bal & ((1ull << lane) - 1ull));
      lists[e * NT + pos] = n;
      wl[e * NT + pos] = eweight[(size_t)n * 16 + e];
      slotpos[e * NT + n] = pos;
    }
    running += tot;
    __syncthreads();
  }
  if (tid == 0) counts[e] = running;
}

// prefix: 256-padded h row bases (+ worklist for fallback path)
__global__ void prefix_kernel(const int* __restrict__ counts, int* __restrict__ base,
                              int* __restrict__ ent, int* __restrict__ nent) {
  if (threadIdx.x == 0 && blockIdx.x == 0) {
    int acc = 0, n = 0;
    for (int e = 0; e < NEXP; ++e) {
      base[e] = acc;
      acc += (counts[e] + 255) & ~255;
      int mt = (counts[e] + 127) >> 7;
      for (int m = 0; m < mt; ++m) ent[n++] = (e << 16) | m;
    }
    *nent = n;
  }
}

// in fp32 [E][K][N] -> out bf16 [E][N][K], 64x64 LDS tiles
__global__ __launch_bounds__(256) void wtrans_kernel(
    const float* __restrict__ in, unsigned short* __restrict__ outp, int K, int N) {
  int e = blockIdx.z;
  int n0 = blockIdx.x * 64;
  int k0 = blockIdx.y * 64;
  const float* src = in + (size_t)e * K * N;
  unsigned short* dst = outp + (size_t)e * K * N;
  __shared__ unsigned short t[64][65];
  int tid = threadIdx.x;
#pragma unroll
  for (int it = 0; it < 4; ++it) {
    int idx = it * 256 + tid;
    int r = idx >> 4, c4 = (idx & 15) << 2;
    float4 v = *(const float4*)(src + (size_t)(k0 + r) * N + n0 + c4);
    t[r][c4 + 0] = f2bf(v.x);
    t[r][c4 + 1] = f2bf(v.y);
    t[r][c4 + 2] = f2bf(v.z);
    t[r][c4 + 3] = f2bf(v.w);
  }
  __syncthreads();
#pragma unroll
  for (int it = 0; it < 4; ++it) {
    int idx = it * 256 + tid;
    int r = idx >> 4, c4 = (idx & 15) << 2;
    ushort4 o;
    o.x = t[c4 + 0][r]; o.y = t[c4 + 1][r];
    o.z = t[c4 + 2][r]; o.w = t[c4 + 3][r];
    *(ushort4*)(dst + (size_t)(n0 + r) * K + k0 + c4) = o;
  }
}

// ======== 128x128 XCD-static persistent GEMMs (4 waves, 32KB LDS, 4 blk/CU) ========
// grid 1024; xcd = b&7 hosts experts xcd, xcd+8; slot = b>>3 (128 slots/XCD);
// m-fastest tile order so concurrent same-XCD slots share the B (weight) n-panel.

// GEMM1: h[hbase+slot, :] = gelu(xb[tok] @ w1t[e]^T + b1[e]); w1t layout [E][DF][DM]
__global__ __launch_bounds__(256, 4) void ffn1s_kernel(
    const unsigned short* __restrict__ xb, const unsigned short* __restrict__ wt,
    const float* __restrict__ b1, const int* __restrict__ counts,
    const int* __restrict__ lists, const int* __restrict__ base,
    unsigned short* __restrict__ h, int cap) {
  const int NN = DF / 128;   // 16 n-tiles
  const int NSLOT = 128;
  int b = blockIdx.x;
  int xcd = b & 7, slot = b >> 3;
  int e0 = xcd, e1 = xcd + 8;
  int c0 = counts[e0], c1 = counts[e1];
  int mt0 = (c0 + 127) >> 7, mt1 = (c1 + 127) >> 7;
  int T0 = mt0 * NN, T = T0 + mt1 * NN;

  __shared__ unsigned short lA[128 * 64];
  __shared__ unsigned short lB[128 * 64];

  int tid = threadIdx.x, lane = tid & 63, wid = tid >> 6;
  int wm = wid >> 1, wn = wid & 1;
  int lrow = lane & 15, lk = lane >> 4;
  int chunk = lane & 7, row_l = lane >> 3;

  for (int k = slot; k < T; k += NSLOT) {
    int e, mti, nt, count;
    if (k < T0) { e = e0; nt = k / mt0; mti = k % mt0; count = c0; }
    else        { int kk = k - T0; e = e1; nt = kk / mt1; mti = kk % mt1; count = c1; }
    int m0 = mti * 128, n0 = nt * 128;
    int hbase = base[e];
    if (hbase + m0 + 128 > cap) continue;
    const unsigned short* we = wt + (size_t)e * DM * DF;  // [DF][DM]
    const int* lst = lists + e * NT + m0;

    const char* asrc[4];
    const char* bsrc[4];
#pragma unroll
    for (int c = 0; c < 4; ++c) {
      int r = wid * 32 + c * 8 + row_l;
      int sc = chunk ^ (r & 7);
      int rr = (m0 + r < count) ? r : 0;
      int tok = lst[rr];
      asrc[c] = (const char*)xb + (size_t)tok * DM * 2 + sc * 16;
      bsrc[c] = (const char*)we + (size_t)(n0 + r) * DM * 2 + sc * 16;
    }

    f32x4 acc[4][4];
#pragma unroll
    for (int m = 0; m < 4; ++m)
#pragma unroll
      for (int n = 0; n < 4; ++n) acc[m][n] = (f32x4)0.0f;

    for (int kt = 0; kt < DM / 64; ++kt) {
      __syncthreads();
#pragma unroll
      for (int c = 0; c < 4; ++c) {
        gload_lds16(asrc[c] + kt * 128, (void*)(lA + (wid * 32 + c * 8) * 64));
        gload_lds16(bsrc[c] + kt * 128, (void*)(lB + (wid * 32 + c * 8) * 64));
      }
      __syncthreads();
#pragma unroll
      for (int ks = 0; ks < 2; ++ks) {
        bf16x8 af[4], bfr[4];
#pragma unroll
        for (int m = 0; m < 4; ++m) {
          int row = wm * 64 + m * 16 + lrow;
          int off = row * 128 + (((ks * 64) + lk * 16) ^ ((row & 7) << 4));
          af[m] = *(const bf16x8*)((const char*)lA + off);
        }
#pragma unroll
        for (int n = 0; n < 4; ++n) {
          int row = wn * 64 + n * 16 + lrow;
          int off = row * 128 + (((ks * 64) + lk * 16) ^ ((row & 7) << 4));
          bfr[n] = *(const bf16x8*)((const char*)lB + off);
        }
#pragma unroll
        for (int m = 0; m < 4; ++m)
#pragma unroll
          for (int n = 0; n < 4; ++n)
            acc[m][n] = __builtin_amdgcn_mfma_f32_16x16x32_bf16(af[m], bfr[n], acc[m][n], 0, 0, 0);
      }
    }
#pragma unroll
    for (int m = 0; m < 4; ++m) {
      int rbase = hbase + m0 + wm * 64 + m * 16 + lk * 4;
#pragma unroll
      for (int n = 0; n < 4; ++n) {
        int col = n0 + wn * 64 + n * 16 + lrow;
        float bias = b1[e * DF + col];
#pragma unroll
        for (int j = 0; j < 4; ++j) {
          float v = acc[m][n][j] + bias;
          h[(size_t)(rbase + j) * DF + col] = f2bf(gelu_f(v));
        }
      }
    }
  }
}

// GEMM2 (y-path): y[hbase+slot, :] = h @ w2t[e]^T  (bf16, no bias, no atomics)
__global__ __launch_bounds__(256, 4) void ffn2y_kernel(
    const unsigned short* __restrict__ h, const unsigned short* __restrict__ wt,
    const int* __restrict__ counts, const int* __restrict__ base,
    unsigned short* __restrict__ y, int cap) {
  const int NN = DM / 128;  // 8 n-tiles
  const int NSLOT = 128;
  int b = blockIdx.x;
  int xcd = b & 7, slot = b >> 3;
  int e0 = xcd, e1 = xcd + 8;
  int c0 = counts[e0], c1 = counts[e1];
  int mt0 = (c0 + 127) >> 7, mt1 = (c1 + 127) >> 7;
  int T0 = mt0 * NN, T = T0 + mt1 * NN;

  __shared__ unsigned short lA[128 * 64];
  __shared__ unsigned short lB[128 * 64];

  int tid = threadIdx.x, lane = tid & 63, wid = tid >> 6;
  int wm = wid >> 1, wn = wid & 1;
  int lrow = lane & 15, lk = lane >> 4;
  int chunk = lane & 7, row_l = lane >> 3;

  for (int k = slot; k < T; k += NSLOT) {
    int e, mti, nt, count;
    if (k < T0) { e = e0; nt = k / mt0; mti = k % mt0; count = c0; }
    else        { int kk = k - T0; e = e1; nt = kk / mt1; mti = kk % mt1; count = c1; }
    int m0 = mti * 128, n0 = nt * 128;
    int hbase = base[e];
    if (hbase + m0 + 128 > cap) continue;
    const unsigned short* we = wt + (size_t)e * DM * DF;  // [DM][DF]

    const char* asrc[4];
    const char* bsrc[4];
#pragma unroll
    for (int c = 0; c < 4; ++c) {
      int r = wid * 32 + c * 8 + row_l;
      int sc = chunk ^ (r & 7);
      asrc[c] = (const char*)h + (size_t)(hbase + m0 + r) * DF * 2 + sc * 16;
      bsrc[c] = (const char*)we + (size_t)(n0 + r) * DF * 2 + sc * 16;
    }

    f32x4 acc[4][4];
#pragma unroll
    for (int m = 0; m < 4; ++m)
#pragma unroll
      for (int n = 0; n < 4; ++n) acc[m][n] = (f32x4)0.0f;

    for (int kt = 0; kt < DF / 64; ++kt) {
      __syncthreads();
#pragma unroll
      for (int c = 0; c < 4; ++c) {
        gload_lds16(asrc[c] + kt * 128, (void*)(lA + (wid * 32 + c * 8) * 64));
        gload_lds16(bsrc[c] + kt * 128, (void*)(lB + (wid * 32 + c * 8) * 64));
      }
      __syncthreads();
#pragma unroll
      for (int ks = 0; ks < 2; ++ks) {
        bf16x8 af[4], bfr[4];
#pragma unroll
        for (int m = 0; m < 4; ++m) {
          int row = wm * 64 + m * 16 + lrow;
          int off = row * 128 + (((ks * 64) + lk * 16) ^ ((row & 7) << 4));
          af[m] = *(const bf16x8*)((const char*)lA + off);
        }
#pragma unroll
        for (int n = 0; n < 4; ++n) {
          int row = wn * 64 + n * 16 + lrow;
          int off = row * 128 + (((ks * 64) + lk * 16) ^ ((row & 7) << 4));
          bfr[n] = *(const bf16x8*)((const char*)lB + off);
        }
#pragma unroll
        for (int m = 0; m < 4; ++m)
#pragma unroll
          for (int n = 0; n < 4; ++n)
            acc[m][n] = __builtin_amdgcn_mfma_f32_16x16x32_bf16(af[m], bfr[n], acc[m][n], 0, 0, 0);
      }
    }
#pragma unroll
    for (int m = 0; m < 4; ++m) {
      int rbase = hbase + m0 + wm * 64 + m * 16 + lk * 4;
      int lcl = m0 + wm * 64 + m * 16 + lk * 4;
#pragma unroll
      for (int n = 0; n < 4; ++n) {
        int col = n0 + wn * 64 + n * 16 + lrow;
#pragma unroll
        for (int j = 0; j < 4; ++j) {
          if (lcl + j < count)
            y[(size_t)(rbase + j) * DM + col] = f2bf(acc[m][n][j]);
        }
      }
    }
  }
}

// final: out[n] = sum_e w * (y[row_e] + b2[e])  (full overwrite of out)
__global__ __launch_bounds__(256) void reduce_kernel(
    const unsigned int* __restrict__ emask, const float* __restrict__ eweight,
    const int* __restrict__ slotpos, const int* __restrict__ base,
    const unsigned short* __restrict__ y, const float* __restrict__ b2,
    float* __restrict__ out) {
  int n = blockIdx.x;
  int tid = threadIdx.x;
  int c = tid * 4;
  unsigned int mask = emask[n];
  float4 accv = make_float4(0.f, 0.f, 0.f, 0.f);
  while (mask) {
    int e = __ffs(mask) - 1;
    mask &= mask - 1;
    float w = eweight[(size_t)n * 16 + e];
    int row = base[e] + slotpos[e * NT + n];
    ushort4 yv = *(const ushort4*)(y + (size_t)row * DM + c);
    float4 bv = *(const float4*)(b2 + e * DM + c);
    accv.x += w * (bf2f(yv.x) + bv.x);
    accv.y += w * (bf2f(yv.y) + bv.y);
    accv.z += w * (bf2f(yv.z) + bv.z);
    accv.w += w * (bf2f(yv.w) + bv.w);
  }
  *(float4*)(out + (size_t)n * DM + c) = accv;
}

// GEMM2 (atomic fallback, static mapping): out[tok] += w * (h @ w2t[e]^T + b2[e])
__global__ __launch_bounds__(256, 4) void ffn2s_kernel(
    const unsigned short* __restrict__ h, const unsigned short* __restrict__ wt,
    const float* __restrict__ b2, const int* __restrict__ counts,
    const int* __restrict__ lists, const int* __restrict__ base,
    const float* __restrict__ wl, float* __restrict__ out, int cap) {
  const int NN = DM / 128;
  const int NSLOT = 128;
  int b = blockIdx.x;
  int xcd = b & 7, slot = b >> 3;
  int e0 = xcd, e1 = xcd + 8;
  int c0 = counts[e0], c1 = counts[e1];
  int mt0 = (c0 + 127) >> 7, mt1 = (c1 + 127) >> 7;
  int T0 = mt0 * NN, T = T0 + mt1 * NN;

  __shared__ unsigned short lA[128 * 64];
  __shared__ unsigned short lB[128 * 64];

  int tid = threadIdx.x, lane = tid & 63, wid = tid >> 6;
  int wm = wid >> 1, wn = wid & 1;
  int lrow = lane & 15, lk = lane >> 4;
  int chunk = lane & 7, row_l = lane >> 3;

  for (int k = slot; k < T; k += NSLOT) {
    int e, mti, nt, count;
    if (k < T0) { e = e0; nt = k / mt0; mti = k % mt0; count = c0; }
    else        { int kk = k - T0; e = e1; nt = kk / mt1; mti = kk % mt1; count = c1; }
    int m0 = mti * 128, n0 = nt * 128;
    int hbase = base[e];
    if (hbase + m0 + 128 > cap) continue;
    const unsigned short* we = wt + (size_t)e * DM * DF;

    const char* asrc[4];
    const char* bsrc[4];
#pragma unroll
    for (int c = 0; c < 4; ++c) {
      int r = wid * 32 + c * 8 + row_l;
      int sc = chunk ^ (r & 7);
      asrc[c] = (const char*)h + (size_t)(hbase + m0 + r) * DF * 2 + sc * 16;
      bsrc[c] = (const char*)we + (size_t)(n0 + r) * DF * 2 + sc * 16;
    }

    f32x4 acc[4][4];
#pragma unroll
    for (int m = 0; m < 4; ++m)
#pragma unroll
      for (int n = 0; n < 4; ++n) acc[m][n] = (f32x4)0.0f;

    for (int kt = 0; kt < DF / 64; ++kt) {
      __syncthreads();
#pragma unroll
      for (int c = 0; c < 4; ++c) {
        gload_lds16(asrc[c] + kt * 128, (void*)(lA + (wid * 32 + c * 8) * 64));
        gload_lds16(bsrc[c] + kt * 128, (void*)(lB + (wid * 32 + c * 8) * 64));
      }
      __syncthreads();
#pragma unroll
      for (int ks = 0; ks < 2; ++ks) {
        bf16x8 af[4], bfr[4];
#pragma unroll
        for (int m = 0; m < 4; ++m) {
          int row = wm * 64 + m * 16 + lrow;
          int off = row * 128 + (((ks * 64) + lk * 16) ^ ((row & 7) << 4));
          af[m] = *(const bf16x8*)((const char*)lA + off);
        }
#pragma unroll
        for (int n = 0; n < 4; ++n) {
          int row = wn * 64 + n * 16 + lrow;
          int off = row * 128 + (((ks * 64) + lk * 16) ^ ((row & 7) << 4));
          bfr[n] = *(const bf16x8*)((const char*)lB + off);
        }
#pragma unroll
        for (int m = 0; m < 4; ++m)
#pragma unroll
          for (int n = 0; n < 4; ++n)
            acc[m][n] = __builtin_amdgcn_mfma_f32_16x16x32_bf16(af[m], bfr[n], acc[m][n], 0, 0, 0);
      }
    }
#pragma unroll
    for (int m = 0; m < 4; ++m) {
      int rbase = m0 + wm * 64 + m * 16 + lk * 4;
#pragma unroll
      for (int n = 0; n < 4; ++n) {
        int col = n0 + wn * 64 + n * 16 + lrow;
        float bias = b2[e * DM + col];
#pragma unroll
        for (int j = 0; j < 4; ++j) {
          int sl = rbase + j;
          if (sl < count) {
            int tok = lists[e * NT + sl];
            float w = wl[e * NT + sl];
            atomicAdd(out + (size_t)tok * DM + col, w * (acc[m][n][j] + bias));
          }
        }
      }
    }
  }
}

// ---------------- fallback GEMMs (fp32 reg-staged, 128^2, small-ws) ----------------
__global__ __launch_bounds__(256) void ffn1_kernel(
    const float* __restrict__ x, const float* __restrict__ w1,
    const float* __restrict__ b1, const int* __restrict__ counts,
    const int* __restrict__ lists, const int* __restrict__ base,
    unsigned short* __restrict__ h, int cap, int e_arg) {
  int e = (e_arg >= 0) ? e_arg : (int)blockIdx.z;
  int count = counts[e];
  int m0 = blockIdx.y * 128;
  if (m0 >= count) return;
  int hbase = base[e];
  if (hbase + m0 + 128 > cap) return;
  int n0 = blockIdx.x * 128;
  const float* w1e = w1 + (size_t)e * DM * DF;
  const int* lst = lists + e * NT + m0;
  __shared__ unsigned short lA[128 * 64];
  __shared__ unsigned short lB[128 * 64];
  int tid = threadIdx.x;
  int lane = tid & 63, wid = tid >> 6;
  int wm = wid >> 1, wn = wid & 1;
  int lrow = lane & 15, lk = lane >> 4;
  f32x4 acc[4][4];
#pragma unroll
  for (int m = 0; m < 4; ++m)
#pragma unroll
    for (int n = 0; n < 4; ++n) acc[m][n] = (f32x4)0.0f;
  for (int kt = 0; kt < DM / 64; ++kt) {
    int k0 = kt * 64;
    __syncthreads();
#pragma unroll
    for (int p = 0; p < 8; ++p) {
      int idx = p * 256 + tid;
      int r = idx >> 4, c4 = idx & 15;
      int tok = (m0 + r < count) ? lst[r] : lst[0];
      float4 v = *(const float4*)(x + (size_t)tok * DM + k0 + c4 * 4);
      ushort4 bv = make_ushort4(f2bf(v.x), f2bf(v.y), f2bf(v.z), f2bf(v.w));
      int off = r * 128 + ((c4 * 8) ^ ((r & 7) << 4));
      *(ushort4*)((char*)lA + off) = bv;
    }
#pragma unroll
    for (int p = 0; p < 16; ++p) {
      int idx = p * 256 + tid;
      int n = idx & 127, k2 = idx >> 7;
      const float* bp = w1e + (size_t)(k0 + 2 * k2) * DF + n0 + n;
      ushort2 bv = make_ushort2(f2bf(bp[0]), f2bf(bp[DF]));
      int off = n * 128 + ((k2 * 4) ^ ((n & 7) << 4));
      *(ushort2*)((char*)lB + off) = bv;
    }
    __syncthreads();
#pragma unroll
    for (int ks = 0; ks < 2; ++ks) {
      bf16x8 af[4], bfr[4];
#pragma unroll
      for (int m = 0; m < 4; ++m) {
        int row = wm * 64 + m * 16 + lrow;
        int off = row * 128 + (((ks * 64) + lk * 16) ^ ((row & 7) << 4));
        af[m] = *(const bf16x8*)((const char*)lA + off);
      }
#pragma unroll
      for (int n = 0; n < 4; ++n) {
        int row = wn * 64 + n * 16 + lrow;
        int off = row * 128 + (((ks * 64) + lk * 16) ^ ((row & 7) << 4));
        bfr[n] = *(const bf16x8*)((const char*)lB + off);
      }
#pragma unroll
      for (int m = 0; m < 4; ++m)
#pragma unroll
        for (int n = 0; n < 4; ++n)
          acc[m][n] = __builtin_amdgcn_mfma_f32_16x16x32_bf16(af[m], bfr[n], acc[m][n], 0, 0, 0);
    }
  }
#pragma unroll
  for (int m = 0; m < 4; ++m) {
    int rbase = hbase + m0 + wm * 64 + m * 16 + lk * 4;
#pragma unroll
    for (int n = 0; n < 4; ++n) {
      int col = n0 + wn * 64 + n * 16 + lrow;
      float bias = b1[e * DF + col];
#pragma unroll
      for (int j = 0; j < 4; ++j) {
        float v = acc[m][n][j] + bias;
        h[(size_t)(rbase + j) * DF + col] = f2bf(gelu_f(v));
      }
    }
  }
}

__global__ __launch_bounds__(256) void ffn2_kernel(
    const unsigned short* __restrict__ h, const float* __restrict__ w2,
    const float* __restrict__ b2, const int* __restrict__ counts,
    const int* __restrict__ lists, const int* __restrict__ base,
    const float* __restrict__ wl, float* __restrict__ out, int cap, int e_arg) {
  int e = (e_arg >= 0) ? e_arg : (int)blockIdx.z;
  int count = counts[e];
  int m0 = blockIdx.y * 128;
  if (m0 >= count) return;
  int hbase = base[e];
  if (hbase + m0 + 128 > cap) return;
  int n0 = blockIdx.x * 128;
  const float* w2e = w2 + (size_t)e * DF * DM;
  __shared__ unsigned short lA[128 * 64];
  __shared__ unsigned short lB[128 * 64];
  int tid = threadIdx.x;
  int lane = tid & 63, wid = tid >> 6;
  int wm = wid >> 1, wn = wid & 1;
  int lrow = lane & 15, lk = lane >> 4;
  f32x4 acc[4][4];
#pragma unroll
  for (int m = 0; m < 4; ++m)
#pragma unroll
    for (int n = 0; n < 4; ++n) acc[m][n] = (f32x4)0.0f;
  for (int kt = 0; kt < DF / 64; ++kt) {
    int k0 = kt * 64;
    __syncthreads();
#pragma unroll
    for (int p = 0; p < 8; ++p) {
      int idx = p * 256 + tid;
      int r = idx >> 4, c4 = idx & 15;
      ushort4 v = *(const ushort4*)(h + (size_t)(hbase + m0 + r) * DF + k0 + c4 * 4);
      int off = r * 128 + ((c4 * 8) ^ ((r & 7) << 4));
      *(ushort4*)((char*)lA + off) = v;
    }
#pragma unroll
    for (int p = 0; p < 16; ++p) {
      int idx = p * 256 + tid;
      int n = idx & 127, k2 = idx >> 7;
      const float* bp = w2e + (size_t)(k0 + 2 * k2) * DM + n0 + n;
      ushort2 bv = make_ushort2(f2bf(bp[0]), f2bf(bp[DM]));
      int off = n * 128 + ((k2 * 4) ^ ((n & 7) << 4));
      *(ushort2*)((char*)lB + off) = bv;
    }
    __syncthreads();
#pragma unroll
    for (int ks = 0; ks < 2; ++ks) {
      bf16x8 af[4], bfr[4];
#pragma unroll
      for (int m = 0; m < 4; ++m) {
        int row = wm * 64 + m * 16 + lrow;
        int off = row * 128 + (((ks * 64) + lk * 16) ^ ((row & 7) << 4));
        af[m] = *(const bf16x8*)((const char*)lA + off);
      }
#pragma unroll
      for (int n = 0; n < 4; ++n) {
        int row = wn * 64 + n * 16 + lrow;
        int off = row * 128 + (((ks * 64) + lk * 16) ^ ((row & 7) << 4));
        bfr[n] = *(const bf16x8*)((const char*)lB + off);
      }
#pragma unroll
      for (int m = 0; m < 4; ++m)
#pragma unroll
        for (int n = 0; n < 4; ++n)
          acc[m][n] = __builtin_amdgcn_mfma_f32_16x16x32_bf16(af[m], bfr[n], acc[m][n], 0, 0, 0);
    }
  }
#pragma unroll
  for (int m = 0; m < 4; ++m) {
    int rbase = m0 + wm * 64 + m * 16 + lk * 4;
#pragma unroll
    for (int n = 0; n < 4; ++n) {
      int col = n0 + wn * 64 + n * 16 + lrow;
      float bias = b2[e * DM + col];
#pragma unroll
      for (int j = 0; j < 4; ++j) {
        int slot = rbase + j;
        if (slot < count) {
          int tok = lists[e * NT + slot];
          float w = wl[e * NT + slot];
          atomicAdd(out + (size_t)tok * DM + col, w * (acc[m][n][j] + bias));
        }
      }
    }
  }
}

extern "C" void kernel_launch(void* const* d_in, const int* in_sizes, int n_in,
                              void* d_out, int out_size, void* d_ws, size_t ws_size,
                              hipStream_t stream) {
  const float* x  = (const float*)d_in[0];
  const float* Wg = (const float*)d_in[1];
  const float* We = (const float*)d_in[2];
  const float* w1 = (const float*)d_in[3];
  const float* b1 = (const float*)d_in[4];
  const float* w2 = (const float*)d_in[5];
  const float* b2 = (const float*)d_in[6];
  float* out = (float*)d_out;

  char* ws = (char*)d_ws;
  int* counts = (int*)ws;                        // 64 B (written by compact)
  int* base   = (int*)(ws + 256);                // 64 B (written by prefix)
  int* nent   = (int*)(ws + 576);                // 1 int (written by prefix)
  int* ent    = (int*)(ws + 1024);               // 2 KB worklist (fallback)
  unsigned int* emask = (unsigned int*)(ws + 4096);            // 16 KB
  int* lists  = (int*)(ws + 32768);                            // 256 KB
  float* wl   = (float*)(ws + 32768 + NEXP * NT * 4);          // 256 KB
  float* eweight = (float*)(ws + 32768 + 2 * NEXP * NT * 4);   // 256 KB
  int* slotpos   = (int*)(ws + 32768 + 3 * NEXP * NT * 4);     // 256 KB

  const size_t OFF_XB = 2u << 20;                               // 2 MB
  const size_t OFF_WT = OFF_XB + ((size_t)NT * DM * 2);         // +8 MB
  const size_t OFF_H  = OFF_WT + ((size_t)NEXP * DM * DF * 2);  // +64 MB
  long cap6 = ((long)ws_size - (long)OFF_H) / (DF * 2 + DM * 2);
  long cap4 = ((long)ws_size - (long)OFF_H) / (DF * 2);
  bool fast = (cap4 >= 20000);
  bool ypath = fast && (cap6 >= 20000);

  unsigned short* xb_router = fast ? (unsigned short*)(ws + OFF_XB) : (unsigned short*)0;

  // out memset only needed for atomic-accumulate paths (y-path fully overwrites out)
  if (!ypath)
    hipMemsetAsync(out, 0, (size_t)NT * DM * sizeof(float), stream);
  router2_kernel<<<NT, 256, 0, stream>>>(x, Wg, We, emask, eweight, xb_router);
  compact_kernel<<<NEXP, 256, 0, stream>>>(emask, eweight, counts, lists, wl, slotpos);

  if (fast) {
    unsigned short* xb = (unsigned short*)(ws + OFF_XB);
    unsigned short* wt = (unsigned short*)(ws + OFF_WT);
    unsigned short* h  = (unsigned short*)(ws + OFF_H);
    prefix_kernel<<<1, 64, 0, stream>>>(counts, base, ent, nent);
    wtrans_kernel<<<dim3(DF / 64, DM / 64, NEXP), 256, 0, stream>>>(w1, wt, DM, DF);
    if (ypath) {
      int cap = (int)(cap6 > 65536 ? 65536 : cap6);
      unsigned short* y = (unsigned short*)(ws + OFF_H + (size_t)cap * DF * 2);
      ffn1s_kernel<<<1024, 256, 0, stream>>>(xb, wt, b1, counts, lists, base, h, cap);
      wtrans_kernel<<<dim3(DM / 64, DF / 64, NEXP), 256, 0, stream>>>(w2, wt, DF, DM);
      ffn2y_kernel<<<1024, 256, 0, stream>>>(h, wt, counts, base, y, cap);
      reduce_kernel<<<NT, 256, 0, stream>>>(emask, eweight, slotpos, base, y, b2, out);
    } else {
      int cap = (int)(cap4 > 65536 ? 65536 : cap4);
      ffn1s_kernel<<<1024, 256, 0, stream>>>(xb, wt, b1, counts, lists, base, h, cap);
      wtrans_kernel<<<dim3(DM / 64, DF / 64, NEXP), 256, 0, stream>>>(w2, wt, DF, DM);
      ffn2s_kernel<<<1024, 256, 0, stream>>>(h, wt, b2, counts, lists, base, wl, out, cap);
    }
  } else {
    unsigned short* h = (unsigned short*)(ws + OFF_XB);
    long cap_rows = ((long)ws_size - (long)OFF_XB) / (DF * 2);
    if (cap_rows >= 24576) {
      int cap = (int)(cap_rows > 65536 ? 65536 : cap_rows);
      prefix_kernel<<<1, 64, 0, stream>>>(counts, base, ent, nent);
      ffn1_kernel<<<dim3(DF / 128, NT / 128, NEXP), 256, 0, stream>>>(
          x, w1, b1, counts, lists, base, h, cap, -1);
      ffn2_kernel<<<dim3(DM / 128, NT / 128, NEXP), 256, 0, stream>>>(
          h, w2, b2, counts, lists, base, wl, out, cap, -1);
    } else {
      prefix_kernel<<<1, 64, 0, stream>>>(counts, base, ent, nent);
      hipMemsetAsync(base, 0, 64, stream);
      for (int e = 0; e < NEXP; ++e) {
        ffn1_kernel<<<dim3(DF / 128, NT / 128, 1), 256, 0, stream>>>(
            x, w1, b1, counts, lists, base, h, NT, e);
        ffn2_kernel<<<dim3(DM / 128, NT / 128, 1), 256, 0, stream>>>(
            h, w2, b2, counts, lists, base, wl, out, NT, e);
      }
    }
  }
}